// Round 1
// baseline (486.878 us; speedup 1.0000x reference)
//
#include <hip/hip_runtime.h>
#include <hip/hip_bf16.h>
#include <cstdint>

#define DIN 16
#define HD  128

static __device__ __forceinline__ void fma4(float4& a, float s, const float4 v) {
    a.x = fmaf(s, v.x, a.x);
    a.y = fmaf(s, v.y, a.y);
    a.z = fmaf(s, v.z, a.z);
    a.w = fmaf(s, v.w, a.w);
}

// ---------------- CSR build ----------------

__global__ void k_zero_int(int* __restrict__ p, int n) {
    int i = blockIdx.x * blockDim.x + threadIdx.x;
    if (i < n) p[i] = 0;
}

__global__ void k_hist(const int* __restrict__ dst, int* __restrict__ cnt, int E) {
    int e = blockIdx.x * blockDim.x + threadIdx.x;
    if (e < E) atomicAdd(&cnt[dst[e]], 1);
}

__global__ void k_dinv(const int* __restrict__ cnt, float* __restrict__ dinv, int N) {
    int i = blockIdx.x * blockDim.x + threadIdx.x;
    if (i < N) dinv[i] = rsqrtf((float)cnt[i] + 1.0f);   // +1 = self-loop
}

// block scans 1024 elements (256 thr x 4); exclusive within block, block total -> bsums
__global__ void k_scan1(const int* __restrict__ in, int* __restrict__ out,
                        int* __restrict__ bsums, int N) {
    __shared__ int sd[256];
    int tid = threadIdx.x;
    int i0 = blockIdx.x * 1024 + tid * 4;
    int v0 = (i0 + 0 < N) ? in[i0 + 0] : 0;
    int v1 = (i0 + 1 < N) ? in[i0 + 1] : 0;
    int v2 = (i0 + 2 < N) ? in[i0 + 2] : 0;
    int v3 = (i0 + 3 < N) ? in[i0 + 3] : 0;
    int ts = v0 + v1 + v2 + v3;
    sd[tid] = ts;
    __syncthreads();
    for (int off = 1; off < 256; off <<= 1) {
        int t = (tid >= off) ? sd[tid - off] : 0;
        __syncthreads();
        sd[tid] += t;
        __syncthreads();
    }
    int eb = sd[tid] - ts;  // exclusive base for this thread
    if (i0 + 0 < N) out[i0 + 0] = eb;
    if (i0 + 1 < N) out[i0 + 1] = eb + v0;
    if (i0 + 2 < N) out[i0 + 2] = eb + v0 + v1;
    if (i0 + 3 < N) out[i0 + 3] = eb + v0 + v1 + v2;
    if (tid == 255) bsums[blockIdx.x] = sd[255];
}

// single-block exclusive scan of block sums (nb <= 256)
__global__ void k_scan2(int* __restrict__ bsums, int nb) {
    __shared__ int sd[256];
    int tid = threadIdx.x;
    int v = (tid < nb) ? bsums[tid] : 0;
    sd[tid] = v;
    __syncthreads();
    for (int off = 1; off < 256; off <<= 1) {
        int t = (tid >= off) ? sd[tid - off] : 0;
        __syncthreads();
        sd[tid] += t;
        __syncthreads();
    }
    if (tid < nb) bsums[tid] = sd[tid] - v;
}

__global__ void k_scan3(int* __restrict__ rowptr, int* __restrict__ cursor,
                        const int* __restrict__ bsums, int N, int E) {
    int i = blockIdx.x * blockDim.x + threadIdx.x;
    if (i < N) {
        int v = rowptr[i] + bsums[i >> 10];
        rowptr[i] = v;
        cursor[i] = v;
    }
    if (i == 0) rowptr[N] = E;
}

__global__ void k_scatter(const int* __restrict__ src, const int* __restrict__ dst,
                          int* __restrict__ cursor, int* __restrict__ colsrc, int E) {
    int e = blockIdx.x * blockDim.x + threadIdx.x;
    if (e < E) {
        int d = dst[e];
        int pos = atomicAdd(&cursor[d], 1);
        colsrc[pos] = src[e];
    }
}

// ---------------- input linear 16->128 + LeakyReLU ----------------

__global__ __launch_bounds__(256) void k_x0(const float* __restrict__ F,
                                            const float* __restrict__ Win,
                                            const float* __restrict__ bin,
                                            float* __restrict__ X0, int N) {
    __shared__ float sW[DIN * HD];   // 8 KB
    __shared__ float sF[8][DIN];
    int tid = threadIdx.x;
    for (int i = tid; i < DIN * HD / 4; i += 256)
        ((float4*)sW)[i] = ((const float4*)Win)[i];
    int nb = blockIdx.x * 8;
    if (tid < 128) {
        int n = tid >> 4, k = tid & 15;
        int node = nb + n;
        sF[n][k] = (node < N) ? F[(size_t)node * DIN + k] : 0.0f;
    }
    __syncthreads();
    int c = (tid & 31) * 4;
    int r = tid >> 5;
    int node = nb + r;
    if (node >= N) return;
    float4 acc = ((const float4*)bin)[c >> 2];
    #pragma unroll
    for (int k = 0; k < DIN; k++) {
        float x = sF[r][k];
        float4 w = *(const float4*)&sW[k * HD + c];
        fma4(acc, x, w);
    }
    acc.x = acc.x > 0.f ? acc.x : 0.01f * acc.x;
    acc.y = acc.y > 0.f ? acc.y : 0.01f * acc.y;
    acc.z = acc.z > 0.f ? acc.z : 0.01f * acc.z;
    acc.w = acc.w > 0.f ? acc.w : 0.01f * acc.w;
    *(float4*)&X0[(size_t)node * HD + c] = acc;
}

// ---------------- dense 128x128 GEMM (per layer) ----------------

__global__ __launch_bounds__(256) void k_gemm(const float* __restrict__ X,
                                              const float* __restrict__ W,
                                              float* __restrict__ Y, int N) {
    __shared__ float sW[HD * HD];    // 64 KB
    __shared__ float sX[32][HD];     // 16 KB
    int tid = threadIdx.x;
    for (int i = tid; i < HD * HD / 4; i += 256)
        ((float4*)sW)[i] = ((const float4*)W)[i];
    int base = blockIdx.x * 32;
    for (int i = tid; i < 32 * HD / 4; i += 256) {
        int n = i >> 5, k4 = i & 31;
        float4 v = make_float4(0.f, 0.f, 0.f, 0.f);
        if (base + n < N) v = ((const float4*)(X + (size_t)(base + n) * HD))[k4];
        ((float4*)&sX[n][0])[k4] = v;
    }
    __syncthreads();
    int c = (tid & 31) * 4;
    int r = (tid >> 5) * 4;
    float4 a0 = make_float4(0.f, 0.f, 0.f, 0.f), a1 = a0, a2 = a0, a3 = a0;
    #pragma unroll 8
    for (int k = 0; k < HD; k++) {
        float4 w = *(const float4*)&sW[k * HD + c];
        float x0 = sX[r + 0][k], x1 = sX[r + 1][k], x2 = sX[r + 2][k], x3 = sX[r + 3][k];
        fma4(a0, x0, w);
        fma4(a1, x1, w);
        fma4(a2, x2, w);
        fma4(a3, x3, w);
    }
    if (base + r + 0 < N) *(float4*)&Y[(size_t)(base + r + 0) * HD + c] = a0;
    if (base + r + 1 < N) *(float4*)&Y[(size_t)(base + r + 1) * HD + c] = a1;
    if (base + r + 2 < N) *(float4*)&Y[(size_t)(base + r + 2) * HD + c] = a2;
    if (base + r + 3 < N) *(float4*)&Y[(size_t)(base + r + 3) * HD + c] = a3;
}

// ---------------- normalized aggregation (CSR, no atomics) ----------------

__global__ __launch_bounds__(256) void k_agg(const float* __restrict__ Hh,
                                             const float* __restrict__ dinv,
                                             const int* __restrict__ rowptr,
                                             const int* __restrict__ colsrc,
                                             const float* __restrict__ bias,
                                             float* __restrict__ out, int N) {
    int tid = threadIdx.x;
    int l = tid & 31;      // 32 lanes x float4 = 128 features
    int sub = tid >> 5;    // 8 nodes per block
    int node = blockIdx.x * 8 + sub;
    if (node >= N) return;
    float di = dinv[node];
    float4 acc = ((const float4*)bias)[l];
    float4 hv = ((const float4*)(Hh + (size_t)node * HD))[l];
    fma4(acc, di * di, hv);                     // self-loop
    int beg = rowptr[node], end = rowptr[node + 1];
    for (int e = beg; e < end; e++) {
        int s = colsrc[e];
        float w = di * dinv[s];
        float4 hs = ((const float4*)(Hh + (size_t)s * HD))[l];
        fma4(acc, w, hs);
    }
    *(float4*)&out[(size_t)node * HD + l * 4] = acc;
}

// ---------------- output head 128->3 ----------------

__global__ __launch_bounds__(256) void k_out(const float* __restrict__ X,
                                             const float* __restrict__ Wout,
                                             const float* __restrict__ bout,
                                             float* __restrict__ out, int N) {
    __shared__ float sW[HD * 3];
    int tid = threadIdx.x;
    for (int i = tid; i < HD * 3; i += 256) sW[i] = Wout[i];
    __syncthreads();
    int lane = tid & 63;
    int wv = tid >> 6;
    int node = blockIdx.x * 4 + wv;
    if (node >= N) return;
    float2 x = ((const float2*)(X + (size_t)node * HD))[lane];
    float p0 = x.x * sW[(2 * lane) * 3 + 0] + x.y * sW[(2 * lane + 1) * 3 + 0];
    float p1 = x.x * sW[(2 * lane) * 3 + 1] + x.y * sW[(2 * lane + 1) * 3 + 1];
    float p2 = x.x * sW[(2 * lane) * 3 + 2] + x.y * sW[(2 * lane + 1) * 3 + 2];
    for (int off = 32; off > 0; off >>= 1) {
        p0 += __shfl_down(p0, off);
        p1 += __shfl_down(p1, off);
        p2 += __shfl_down(p2, off);
    }
    if (lane == 0) {
        out[(size_t)node * 3 + 0] = p0 + bout[0];
        out[(size_t)node * 3 + 1] = p1 + bout[1];
        out[(size_t)node * 3 + 2] = p2 + bout[2];
    }
}

extern "C" void kernel_launch(void* const* d_in, const int* in_sizes, int n_in,
                              void* d_out, int out_size, void* d_ws, size_t ws_size,
                              hipStream_t stream) {
    const float* feat = (const float*)d_in[0];
    const int*   ei   = (const int*)d_in[1];
    // d_in[2] edge_type: unused (as in reference)
    const float* Win  = (const float*)d_in[3];
    const float* bin  = (const float*)d_in[4];
    const float* W1   = (const float*)d_in[5];
    const float* b1   = (const float*)d_in[6];
    const float* W2   = (const float*)d_in[7];
    const float* b2   = (const float*)d_in[8];
    const float* Wout = (const float*)d_in[9];
    const float* bout = (const float*)d_in[10];
    float* out = (float*)d_out;

    int N = in_sizes[0] / DIN;
    int E = in_sizes[2];
    const int* src = ei;
    const int* dst = ei + E;

    char* p = (char*)d_ws;
    auto alloc = [&](size_t bytes) -> char* {
        char* q = p;
        p += (bytes + 511) & ~(size_t)511;
        return q;
    };
    float* bufA   = (float*)alloc((size_t)N * HD * 4);
    float* bufB   = (float*)alloc((size_t)N * HD * 4);
    float* dinv   = (float*)alloc((size_t)N * 4);
    int*   rowptr = (int*)alloc((size_t)(N + 1) * 4);
    int*   cursor = (int*)alloc((size_t)N * 4);
    int*   colsrc = (int*)alloc((size_t)E * 4);
    int NB = (N + 1023) / 1024;
    int*   bsums  = (int*)alloc((size_t)NB * 4);

    // CSR build (every launch; ws is re-poisoned)
    k_zero_int<<<(N + 255) / 256, 256, 0, stream>>>(cursor, N);
    k_hist<<<(E + 255) / 256, 256, 0, stream>>>(dst, cursor, E);
    k_dinv<<<(N + 255) / 256, 256, 0, stream>>>(cursor, dinv, N);
    k_scan1<<<NB, 256, 0, stream>>>(cursor, rowptr, bsums, N);
    k_scan2<<<1, 256, 0, stream>>>(bsums, NB);
    k_scan3<<<(N + 255) / 256, 256, 0, stream>>>(rowptr, cursor, bsums, N, E);
    k_scatter<<<(E + 255) / 256, 256, 0, stream>>>(src, dst, cursor, colsrc, E);

    // network
    k_x0<<<(N + 7) / 8, 256, 0, stream>>>(feat, Win, bin, bufA, N);
    k_gemm<<<(N + 31) / 32, 256, 0, stream>>>(bufA, W1, bufB, N);
    k_agg<<<(N + 7) / 8, 256, 0, stream>>>(bufB, dinv, rowptr, colsrc, b1, bufA, N);
    k_gemm<<<(N + 31) / 32, 256, 0, stream>>>(bufA, W2, bufB, N);
    k_agg<<<(N + 7) / 8, 256, 0, stream>>>(bufB, dinv, rowptr, colsrc, b2, bufA, N);
    k_out<<<(N + 3) / 4, 256, 0, stream>>>(bufA, Wout, bout, out, N);
}

// Round 2
// 476.368 us; speedup vs baseline: 1.0221x; 1.0221x over previous
//
#include <hip/hip_runtime.h>
#include <hip/hip_bf16.h>
#include <cstdint>

#define DIN 16
#define HD  128

static __device__ __forceinline__ void fma4(float4& a, float s, const float4 v) {
    a.x = fmaf(s, v.x, a.x);
    a.y = fmaf(s, v.y, a.y);
    a.z = fmaf(s, v.z, a.z);
    a.w = fmaf(s, v.w, a.w);
}

static __device__ __forceinline__ float bf2f(unsigned short u) {
    union { unsigned u; float f; } x;
    x.u = ((unsigned)u) << 16;
    return x.f;
}
static __device__ __forceinline__ unsigned short f2bf(float f) {
    union { float f; unsigned u; } x;
    x.f = f;
    unsigned r = x.u + 0x7fff + ((x.u >> 16) & 1);   // RNE
    return (unsigned short)(r >> 16);
}
static __device__ __forceinline__ float4 bf4_to_f4(ushort4 v) {
    return make_float4(bf2f(v.x), bf2f(v.y), bf2f(v.z), bf2f(v.w));
}
static __device__ __forceinline__ ushort4 f4_to_bf4(float4 v) {
    ushort4 o;
    o.x = f2bf(v.x); o.y = f2bf(v.y); o.z = f2bf(v.z); o.w = f2bf(v.w);
    return o;
}

// ---------------- CSR build ----------------

__global__ void k_hist(const int* __restrict__ dst, int* __restrict__ cnt, int E) {
    int e = blockIdx.x * blockDim.x + threadIdx.x;
    if (e < E) atomicAdd(&cnt[dst[e]], 1);
}

// block scans 1024 elements (256 thr x 4); exclusive within block, block total -> bsums.
// Also emits dinv = rsqrt(cnt+1) (self-loop included).
__global__ void k_scan1(const int* __restrict__ in, int* __restrict__ out,
                        int* __restrict__ bsums, float* __restrict__ dinv, int N) {
    __shared__ int sd[256];
    int tid = threadIdx.x;
    int i0 = blockIdx.x * 1024 + tid * 4;
    int v0 = (i0 + 0 < N) ? in[i0 + 0] : 0;
    int v1 = (i0 + 1 < N) ? in[i0 + 1] : 0;
    int v2 = (i0 + 2 < N) ? in[i0 + 2] : 0;
    int v3 = (i0 + 3 < N) ? in[i0 + 3] : 0;
    int ts = v0 + v1 + v2 + v3;
    sd[tid] = ts;
    __syncthreads();
    for (int off = 1; off < 256; off <<= 1) {
        int t = (tid >= off) ? sd[tid - off] : 0;
        __syncthreads();
        sd[tid] += t;
        __syncthreads();
    }
    int eb = sd[tid] - ts;  // exclusive base for this thread
    if (i0 + 0 < N) { out[i0 + 0] = eb;                dinv[i0 + 0] = rsqrtf((float)v0 + 1.0f); }
    if (i0 + 1 < N) { out[i0 + 1] = eb + v0;           dinv[i0 + 1] = rsqrtf((float)v1 + 1.0f); }
    if (i0 + 2 < N) { out[i0 + 2] = eb + v0 + v1;      dinv[i0 + 2] = rsqrtf((float)v2 + 1.0f); }
    if (i0 + 3 < N) { out[i0 + 3] = eb + v0 + v1 + v2; dinv[i0 + 3] = rsqrtf((float)v3 + 1.0f); }
    if (tid == 255) bsums[blockIdx.x] = sd[255];
}

// single-block exclusive scan of block sums (nb <= 256)
__global__ void k_scan2(int* __restrict__ bsums, int nb) {
    __shared__ int sd[256];
    int tid = threadIdx.x;
    int v = (tid < nb) ? bsums[tid] : 0;
    sd[tid] = v;
    __syncthreads();
    for (int off = 1; off < 256; off <<= 1) {
        int t = (tid >= off) ? sd[tid - off] : 0;
        __syncthreads();
        sd[tid] += t;
        __syncthreads();
    }
    if (tid < nb) bsums[tid] = sd[tid] - v;
}

__global__ void k_scan3(int* __restrict__ rowptr, int* __restrict__ cursor,
                        const int* __restrict__ bsums, int N, int E) {
    int i = blockIdx.x * blockDim.x + threadIdx.x;
    if (i < N) {
        int v = rowptr[i] + bsums[i >> 10];
        rowptr[i] = v;
        cursor[i] = v;
    }
    if (i == 0) rowptr[N] = E;
}

__global__ void k_scatter(const int* __restrict__ src, const int* __restrict__ dst,
                          int* __restrict__ cursor, int* __restrict__ colsrc, int E) {
    int e = blockIdx.x * blockDim.x + threadIdx.x;
    if (e < E) {
        int d = dst[e];
        int pos = atomicAdd(&cursor[d], 1);
        colsrc[pos] = src[e];
    }
}

// ---------------- input linear 16->128 + LeakyReLU (bf16 out) ----------------

__global__ __launch_bounds__(256) void k_x0(const float* __restrict__ F,
                                            const float* __restrict__ Win,
                                            const float* __restrict__ bin,
                                            unsigned short* __restrict__ X0, int N) {
    __shared__ float sW[DIN * HD];   // 8 KB
    __shared__ float sF[8][DIN];
    int tid = threadIdx.x;
    for (int i = tid; i < DIN * HD / 4; i += 256)
        ((float4*)sW)[i] = ((const float4*)Win)[i];
    int nb = blockIdx.x * 8;
    if (tid < 128) {
        int n = tid >> 4, k = tid & 15;
        int node = nb + n;
        sF[n][k] = (node < N) ? F[(size_t)node * DIN + k] : 0.0f;
    }
    __syncthreads();
    int c = (tid & 31) * 4;
    int r = tid >> 5;
    int node = nb + r;
    if (node >= N) return;
    float4 acc = ((const float4*)bin)[c >> 2];
    #pragma unroll
    for (int k = 0; k < DIN; k++) {
        float x = sF[r][k];
        float4 w = *(const float4*)&sW[k * HD + c];
        fma4(acc, x, w);
    }
    acc.x = acc.x > 0.f ? acc.x : 0.01f * acc.x;
    acc.y = acc.y > 0.f ? acc.y : 0.01f * acc.y;
    acc.z = acc.z > 0.f ? acc.z : 0.01f * acc.z;
    acc.w = acc.w > 0.f ? acc.w : 0.01f * acc.w;
    *(ushort4*)&X0[(size_t)node * HD + c] = f4_to_bf4(acc);
}

// ---------------- dense 128x128 GEMM, bf16 in / bf16 out, fp32 accum ----------------

__global__ __launch_bounds__(256) void k_gemm(const unsigned short* __restrict__ X,
                                              const float* __restrict__ W,
                                              unsigned short* __restrict__ Y, int N) {
    __shared__ float sW[HD * HD];    // 64 KB
    __shared__ float sX[32][HD];     // 16 KB
    int tid = threadIdx.x;
    for (int i = tid; i < HD * HD / 4; i += 256)
        ((float4*)sW)[i] = ((const float4*)W)[i];
    int base = blockIdx.x * 32;
    for (int i = tid; i < 32 * HD / 4; i += 256) {     // 1024 ushort4 chunks
        int n = i >> 5, k4 = i & 31;
        float4 v = make_float4(0.f, 0.f, 0.f, 0.f);
        if (base + n < N)
            v = bf4_to_f4(((const ushort4*)(X + (size_t)(base + n) * HD))[k4]);
        ((float4*)&sX[n][0])[k4] = v;
    }
    __syncthreads();
    int c = (tid & 31) * 4;
    int r = (tid >> 5) * 4;
    float4 a0 = make_float4(0.f, 0.f, 0.f, 0.f), a1 = a0, a2 = a0, a3 = a0;
    #pragma unroll 8
    for (int k = 0; k < HD; k++) {
        float4 w = *(const float4*)&sW[k * HD + c];
        float x0 = sX[r + 0][k], x1 = sX[r + 1][k], x2 = sX[r + 2][k], x3 = sX[r + 3][k];
        fma4(a0, x0, w);
        fma4(a1, x1, w);
        fma4(a2, x2, w);
        fma4(a3, x3, w);
    }
    if (base + r + 0 < N) *(ushort4*)&Y[(size_t)(base + r + 0) * HD + c] = f4_to_bf4(a0);
    if (base + r + 1 < N) *(ushort4*)&Y[(size_t)(base + r + 1) * HD + c] = f4_to_bf4(a1);
    if (base + r + 2 < N) *(ushort4*)&Y[(size_t)(base + r + 2) * HD + c] = f4_to_bf4(a2);
    if (base + r + 3 < N) *(ushort4*)&Y[(size_t)(base + r + 3) * HD + c] = f4_to_bf4(a3);
}

// ---------------- normalized aggregation (CSR, bf16 gather, bf16 out) ----------------

__global__ __launch_bounds__(256) void k_agg(const unsigned short* __restrict__ Hb,
                                             const float* __restrict__ dinv,
                                             const int* __restrict__ rowptr,
                                             const int* __restrict__ colsrc,
                                             const float* __restrict__ bias,
                                             unsigned short* __restrict__ outb, int N) {
    int tid = threadIdx.x;
    int l = tid & 31;      // 32 lanes x 4 bf16 = 128 features
    int sub = tid >> 5;    // 8 nodes per block
    int node = blockIdx.x * 8 + sub;
    if (node >= N) return;
    float di = dinv[node];
    float4 acc = ((const float4*)bias)[l];
    float4 hv = bf4_to_f4(((const ushort4*)(Hb + (size_t)node * HD))[l]);
    fma4(acc, di * di, hv);                     // self-loop
    int beg = rowptr[node], end = rowptr[node + 1];
    for (int e = beg; e < end; e++) {
        int s = colsrc[e];
        float w = di * dinv[s];
        float4 hs = bf4_to_f4(((const ushort4*)(Hb + (size_t)s * HD))[l]);
        fma4(acc, w, hs);
    }
    *(ushort4*)&outb[(size_t)node * HD + l * 4] = f4_to_bf4(acc);
}

// ---------------- aggregation + fused output head 128->3 (fp32 out) ----------------

__global__ __launch_bounds__(256) void k_agg_head(const unsigned short* __restrict__ Hb,
                                                  const float* __restrict__ dinv,
                                                  const int* __restrict__ rowptr,
                                                  const int* __restrict__ colsrc,
                                                  const float* __restrict__ bias,
                                                  const float* __restrict__ Wout,
                                                  const float* __restrict__ bout,
                                                  float* __restrict__ out, int N) {
    __shared__ float sWo[HD * 3];
    int tid = threadIdx.x;
    for (int i = tid; i < HD * 3; i += 256) sWo[i] = Wout[i];
    __syncthreads();
    int l = tid & 31;
    int sub = tid >> 5;
    int node = blockIdx.x * 8 + sub;
    if (node >= N) return;
    float di = dinv[node];
    float4 acc = ((const float4*)bias)[l];
    float4 hv = bf4_to_f4(((const ushort4*)(Hb + (size_t)node * HD))[l]);
    fma4(acc, di * di, hv);
    int beg = rowptr[node], end = rowptr[node + 1];
    for (int e = beg; e < end; e++) {
        int s = colsrc[e];
        float w = di * dinv[s];
        float4 hs = bf4_to_f4(((const ushort4*)(Hb + (size_t)s * HD))[l]);
        fma4(acc, w, hs);
    }
    // head: y[j] = sum_k acc_k * Wout[k][j]  (k = 4l..4l+3 on this lane)
    float p0 = acc.x * sWo[(4 * l + 0) * 3 + 0] + acc.y * sWo[(4 * l + 1) * 3 + 0]
             + acc.z * sWo[(4 * l + 2) * 3 + 0] + acc.w * sWo[(4 * l + 3) * 3 + 0];
    float p1 = acc.x * sWo[(4 * l + 0) * 3 + 1] + acc.y * sWo[(4 * l + 1) * 3 + 1]
             + acc.z * sWo[(4 * l + 2) * 3 + 1] + acc.w * sWo[(4 * l + 3) * 3 + 1];
    float p2 = acc.x * sWo[(4 * l + 0) * 3 + 2] + acc.y * sWo[(4 * l + 1) * 3 + 2]
             + acc.z * sWo[(4 * l + 2) * 3 + 2] + acc.w * sWo[(4 * l + 3) * 3 + 2];
    for (int off = 16; off > 0; off >>= 1) {
        p0 += __shfl_down(p0, off, 32);
        p1 += __shfl_down(p1, off, 32);
        p2 += __shfl_down(p2, off, 32);
    }
    if (l == 0) {
        out[(size_t)node * 3 + 0] = p0 + bout[0];
        out[(size_t)node * 3 + 1] = p1 + bout[1];
        out[(size_t)node * 3 + 2] = p2 + bout[2];
    }
}

extern "C" void kernel_launch(void* const* d_in, const int* in_sizes, int n_in,
                              void* d_out, int out_size, void* d_ws, size_t ws_size,
                              hipStream_t stream) {
    const float* feat = (const float*)d_in[0];
    const int*   ei   = (const int*)d_in[1];
    // d_in[2] edge_type: unused (as in reference)
    const float* Win  = (const float*)d_in[3];
    const float* bin  = (const float*)d_in[4];
    const float* W1   = (const float*)d_in[5];
    const float* b1   = (const float*)d_in[6];
    const float* W2   = (const float*)d_in[7];
    const float* b2   = (const float*)d_in[8];
    const float* Wout = (const float*)d_in[9];
    const float* bout = (const float*)d_in[10];
    float* out = (float*)d_out;

    int N = in_sizes[0] / DIN;
    int E = in_sizes[2];
    const int* src = ei;
    const int* dst = ei + E;

    char* p = (char*)d_ws;
    auto alloc = [&](size_t bytes) -> char* {
        char* q = p;
        p += (bytes + 511) & ~(size_t)511;
        return q;
    };
    unsigned short* bufA = (unsigned short*)alloc((size_t)N * HD * 2);  // bf16 activations
    unsigned short* bufB = (unsigned short*)alloc((size_t)N * HD * 2);
    float* dinv   = (float*)alloc((size_t)N * 4);
    int*   rowptr = (int*)alloc((size_t)(N + 1) * 4);
    int*   cnt    = (int*)alloc((size_t)N * 4);       // histogram, then cursor
    int*   colsrc = (int*)alloc((size_t)E * 4);
    int NB = (N + 1023) / 1024;
    int*   bsums  = (int*)alloc((size_t)NB * 4);

    // CSR build (every launch; ws is re-poisoned)
    hipMemsetAsync(cnt, 0, (size_t)N * 4, stream);
    k_hist<<<(E + 255) / 256, 256, 0, stream>>>(dst, cnt, E);
    k_scan1<<<NB, 256, 0, stream>>>(cnt, rowptr, bsums, dinv, N);
    k_scan2<<<1, 256, 0, stream>>>(bsums, NB);
    k_scan3<<<(N + 255) / 256, 256, 0, stream>>>(rowptr, cnt, bsums, N, E);
    k_scatter<<<(E + 255) / 256, 256, 0, stream>>>(src, dst, cnt, colsrc, E);

    // network
    k_x0<<<(N + 7) / 8, 256, 0, stream>>>(feat, Win, bin, bufA, N);
    k_gemm<<<(N + 31) / 32, 256, 0, stream>>>(bufA, W1, bufB, N);
    k_agg<<<(N + 7) / 8, 256, 0, stream>>>(bufB, dinv, rowptr, colsrc, b1, bufA, N);
    k_gemm<<<(N + 31) / 32, 256, 0, stream>>>(bufA, W2, bufB, N);
    k_agg_head<<<(N + 7) / 8, 256, 0, stream>>>(bufB, dinv, rowptr, colsrc, b2,
                                                Wout, bout, out, N);
}

// Round 3
// 236.292 us; speedup vs baseline: 2.0605x; 2.0160x over previous
//
#include <hip/hip_runtime.h>
#include <hip/hip_bf16.h>
#include <cstdint>

#define DIN 16
#define HD  128

static __device__ __forceinline__ void fma4(float4& a, float s, const float4 v) {
    a.x = fmaf(s, v.x, a.x);
    a.y = fmaf(s, v.y, a.y);
    a.z = fmaf(s, v.z, a.z);
    a.w = fmaf(s, v.w, a.w);
}

// ---------------- CSR build ----------------

__global__ void k_hist(const int* __restrict__ dst, int* __restrict__ cnt, int E) {
    int e = blockIdx.x * blockDim.x + threadIdx.x;
    if (e < E) atomicAdd(&cnt[dst[e]], 1);
}

// block scans 1024 counts (256 thr x 4); exclusive within block, block total -> bsums.
// Also emits dinv = rsqrt(cnt+1) (self-loop included).
__global__ void k_scan1(const int* __restrict__ in, int* __restrict__ out,
                        int* __restrict__ bsums, float* __restrict__ dinv, int N) {
    __shared__ int sd[256];
    int tid = threadIdx.x;
    int i0 = blockIdx.x * 1024 + tid * 4;
    int v0 = (i0 + 0 < N) ? in[i0 + 0] : 0;
    int v1 = (i0 + 1 < N) ? in[i0 + 1] : 0;
    int v2 = (i0 + 2 < N) ? in[i0 + 2] : 0;
    int v3 = (i0 + 3 < N) ? in[i0 + 3] : 0;
    int ts = v0 + v1 + v2 + v3;
    sd[tid] = ts;
    __syncthreads();
    for (int off = 1; off < 256; off <<= 1) {
        int t = (tid >= off) ? sd[tid - off] : 0;
        __syncthreads();
        sd[tid] += t;
        __syncthreads();
    }
    int eb = sd[tid] - ts;
    if (i0 + 0 < N) { out[i0 + 0] = eb;                dinv[i0 + 0] = rsqrtf((float)v0 + 1.0f); }
    if (i0 + 1 < N) { out[i0 + 1] = eb + v0;           dinv[i0 + 1] = rsqrtf((float)v1 + 1.0f); }
    if (i0 + 2 < N) { out[i0 + 2] = eb + v0 + v1;      dinv[i0 + 2] = rsqrtf((float)v2 + 1.0f); }
    if (i0 + 3 < N) { out[i0 + 3] = eb + v0 + v1 + v2; dinv[i0 + 3] = rsqrtf((float)v3 + 1.0f); }
    if (tid == 255) bsums[blockIdx.x] = sd[255];
}

__global__ void k_scan2(int* __restrict__ bsums, int nb) {
    __shared__ int sd[256];
    int tid = threadIdx.x;
    int v = (tid < nb) ? bsums[tid] : 0;
    sd[tid] = v;
    __syncthreads();
    for (int off = 1; off < 256; off <<= 1) {
        int t = (tid >= off) ? sd[tid - off] : 0;
        __syncthreads();
        sd[tid] += t;
        __syncthreads();
    }
    if (tid < nb) bsums[tid] = sd[tid] - v;
}

__global__ void k_scan3(int* __restrict__ rowptr, int* __restrict__ cursor,
                        const int* __restrict__ bsums, int N, int E) {
    int i = blockIdx.x * blockDim.x + threadIdx.x;
    if (i < N) {
        int v = rowptr[i] + bsums[i >> 10];
        rowptr[i] = v;
        cursor[i] = v;
    }
    if (i == 0) rowptr[N] = E;
}

// pack (src, w=dinv[src]*dinv[dst]) per edge, bucketed by dst
__global__ void k_scatter(const int* __restrict__ src, const int* __restrict__ dst,
                          int* __restrict__ cursor, const float* __restrict__ dinv,
                          int2* __restrict__ edges, int E) {
    int e = blockIdx.x * blockDim.x + threadIdx.x;
    if (e < E) {
        int s = src[e];
        int d = dst[e];
        float w = dinv[s] * dinv[d];
        int pos = atomicAdd(&cursor[d], 1);
        edges[pos] = make_int2(s, __float_as_int(w));
    }
}

// ---------------- fold weights: Wc = W1*W2*Wout, c1 = (W2*Wout)^T b1, b'' = Wout^T b2 + bout
// single block of 256 threads; Wcp is [128] float4 (wc0,wc1,wc2,0); cbuf[0..2]=c1, cbuf[3..5]=b''
__global__ __launch_bounds__(256) void k_wc(const float* __restrict__ W1,
                                            const float* __restrict__ b1,
                                            const float* __restrict__ W2,
                                            const float* __restrict__ b2,
                                            const float* __restrict__ Wout,
                                            const float* __restrict__ bout,
                                            float4* __restrict__ Wcp,
                                            float* __restrict__ cbuf) {
    __shared__ float sT[HD * 3];   // T = W2 @ Wout
    int tid = threadIdx.x;
    for (int idx = tid; idx < HD * 3; idx += 256) {
        int k = idx / 3, o = idx - 3 * k;
        float s = 0.f;
        for (int j = 0; j < HD; j++) s = fmaf(W2[k * HD + j], Wout[j * 3 + o], s);
        sT[idx] = s;
    }
    if (tid < 3) {  // b'' (independent of T)
        float s = bout[tid];
        for (int j = 0; j < HD; j++) s = fmaf(b2[j], Wout[j * 3 + tid], s);
        cbuf[3 + tid] = s;
    }
    __syncthreads();
    if (tid < 3) {  // c1 = T^T b1
        float s = 0.f;
        for (int j = 0; j < HD; j++) s = fmaf(b1[j], sT[j * 3 + tid], s);
        cbuf[tid] = s;
    }
    for (int idx = tid; idx < HD * 3; idx += 256) {
        int k = idx / 3, o = idx - 3 * k;
        float s = 0.f;
        for (int j = 0; j < HD; j++) s = fmaf(W1[k * HD + j], sT[j * 3 + o], s);
        ((float*)&Wcp[k])[o] = s;
    }
    for (int idx = tid; idx < HD; idx += 256) ((float*)&Wcp[idx])[3] = 0.f;
}

// ---------------- Y0 = leakyrelu(F @ Win + bin) @ Wc, stored [N] float4 (y0,y1,y2,1)
// 16 lanes per node, 16 nodes per block
__global__ __launch_bounds__(256) void k_x0y(const float* __restrict__ F,
                                             const float* __restrict__ Win,
                                             const float* __restrict__ bin,
                                             const float4* __restrict__ Wcp,
                                             float4* __restrict__ Y, int N) {
    __shared__ float4 sWin[DIN * HD / 4];  // 8 KB, row k = 32 float4
    __shared__ float4 sWc[HD];             // 2 KB
    __shared__ float4 sBin[HD / 4];        // 512 B
    __shared__ float  sF[16 * DIN];        // 1 KB
    int tid = threadIdx.x;
    for (int i = tid; i < DIN * HD / 4; i += 256) sWin[i] = ((const float4*)Win)[i];
    for (int i = tid; i < HD; i += 256) sWc[i] = Wcp[i];
    if (tid < HD / 4) sBin[tid] = ((const float4*)bin)[tid];
    int base = blockIdx.x * 16;
    {
        int node = base + (tid >> 4);
        sF[tid] = (node < N) ? F[(size_t)base * DIN + tid] : 0.f;
    }
    __syncthreads();
    int l = tid & 15;        // lane within node-group: owns output features 8l..8l+7
    int g = tid >> 4;        // node group
    int node = base + g;
    if (node >= N) return;
    float4 h0 = sBin[l * 2 + 0];
    float4 h1 = sBin[l * 2 + 1];
    #pragma unroll
    for (int k = 0; k < DIN; k++) {
        float f = sF[g * DIN + k];
        fma4(h0, f, sWin[k * 32 + l * 2 + 0]);
        fma4(h1, f, sWin[k * 32 + l * 2 + 1]);
    }
    h0.x = h0.x > 0.f ? h0.x : 0.01f * h0.x;
    h0.y = h0.y > 0.f ? h0.y : 0.01f * h0.y;
    h0.z = h0.z > 0.f ? h0.z : 0.01f * h0.z;
    h0.w = h0.w > 0.f ? h0.w : 0.01f * h0.w;
    h1.x = h1.x > 0.f ? h1.x : 0.01f * h1.x;
    h1.y = h1.y > 0.f ? h1.y : 0.01f * h1.y;
    h1.z = h1.z > 0.f ? h1.z : 0.01f * h1.z;
    h1.w = h1.w > 0.f ? h1.w : 0.01f * h1.w;
    float a0 = 0.f, a1 = 0.f, a2 = 0.f;
    const float* hh = (const float*)&h0;   // h0,h1 contiguous? not guaranteed — do explicitly
    float hv[8] = {h0.x, h0.y, h0.z, h0.w, h1.x, h1.y, h1.z, h1.w};
    #pragma unroll
    for (int jj = 0; jj < 8; jj++) {
        float4 wc = sWc[l * 8 + jj];
        a0 = fmaf(hv[jj], wc.x, a0);
        a1 = fmaf(hv[jj], wc.y, a1);
        a2 = fmaf(hv[jj], wc.z, a2);
    }
    (void)hh;
    #pragma unroll
    for (int off = 8; off > 0; off >>= 1) {
        a0 += __shfl_down(a0, off, 16);
        a1 += __shfl_down(a1, off, 16);
        a2 += __shfl_down(a2, off, 16);
    }
    if (l == 0) Y[node] = make_float4(a0, a1, a2, 1.0f);
}

// ---------------- aggregation pass A: Z = A * Y   (thread per node, [N,4])
__global__ __launch_bounds__(256) void k_aggA(const float4* __restrict__ Y,
                                              const float* __restrict__ dinv,
                                              const int* __restrict__ rowptr,
                                              const int2* __restrict__ edges,
                                              float4* __restrict__ Z, int N) {
    int n = blockIdx.x * blockDim.x + threadIdx.x;
    if (n >= N) return;
    float di = dinv[n];
    float4 acc = make_float4(0.f, 0.f, 0.f, 0.f);
    fma4(acc, di * di, Y[n]);                      // self-loop
    int e = rowptr[n], end = rowptr[n + 1];
    for (; e + 3 < end; e += 4) {
        int2 e0 = edges[e + 0], e1 = edges[e + 1], e2 = edges[e + 2], e3 = edges[e + 3];
        float4 y0 = Y[e0.x], y1 = Y[e1.x], y2 = Y[e2.x], y3 = Y[e3.x];
        fma4(acc, __int_as_float(e0.y), y0);
        fma4(acc, __int_as_float(e1.y), y1);
        fma4(acc, __int_as_float(e2.y), y2);
        fma4(acc, __int_as_float(e3.y), y3);
    }
    for (; e < end; e++) {
        int2 ed = edges[e];
        fma4(acc, __int_as_float(ed.y), Y[ed.x]);
    }
    Z[n] = acc;
}

// ---------------- aggregation pass B + epilogue: out = (A*Z)[:,0:3] + r*c1 + b''
__global__ __launch_bounds__(256) void k_aggB(const float4* __restrict__ Z,
                                              const float* __restrict__ dinv,
                                              const int* __restrict__ rowptr,
                                              const int2* __restrict__ edges,
                                              const float* __restrict__ cbuf,
                                              float* __restrict__ out, int N) {
    int n = blockIdx.x * blockDim.x + threadIdx.x;
    if (n >= N) return;
    float di = dinv[n];
    float4 zself = Z[n];
    float r = zself.w;                              // r[n] = (A*1)[n], carried in channel 3
    float4 acc = make_float4(0.f, 0.f, 0.f, 0.f);
    fma4(acc, di * di, zself);
    int e = rowptr[n], end = rowptr[n + 1];
    for (; e + 3 < end; e += 4) {
        int2 e0 = edges[e + 0], e1 = edges[e + 1], e2 = edges[e + 2], e3 = edges[e + 3];
        float4 z0 = Z[e0.x], z1 = Z[e1.x], z2 = Z[e2.x], z3 = Z[e3.x];
        fma4(acc, __int_as_float(e0.y), z0);
        fma4(acc, __int_as_float(e1.y), z1);
        fma4(acc, __int_as_float(e2.y), z2);
        fma4(acc, __int_as_float(e3.y), z3);
    }
    for (; e < end; e++) {
        int2 ed = edges[e];
        fma4(acc, __int_as_float(ed.y), Z[ed.x]);
    }
    out[(size_t)n * 3 + 0] = acc.x + r * cbuf[0] + cbuf[3];
    out[(size_t)n * 3 + 1] = acc.y + r * cbuf[1] + cbuf[4];
    out[(size_t)n * 3 + 2] = acc.z + r * cbuf[2] + cbuf[5];
}

extern "C" void kernel_launch(void* const* d_in, const int* in_sizes, int n_in,
                              void* d_out, int out_size, void* d_ws, size_t ws_size,
                              hipStream_t stream) {
    const float* feat = (const float*)d_in[0];
    const int*   ei   = (const int*)d_in[1];
    // d_in[2] edge_type: unused (as in reference)
    const float* Win  = (const float*)d_in[3];
    const float* bin  = (const float*)d_in[4];
    const float* W1   = (const float*)d_in[5];
    const float* b1   = (const float*)d_in[6];
    const float* W2   = (const float*)d_in[7];
    const float* b2   = (const float*)d_in[8];
    const float* Wout = (const float*)d_in[9];
    const float* bout = (const float*)d_in[10];
    float* out = (float*)d_out;

    int N = in_sizes[0] / DIN;
    int E = in_sizes[2];
    const int* src = ei;
    const int* dst = ei + E;

    char* p = (char*)d_ws;
    auto alloc = [&](size_t bytes) -> char* {
        char* q = p;
        p += (bytes + 511) & ~(size_t)511;
        return q;
    };
    float4* Y      = (float4*)alloc((size_t)N * 16);
    float4* Z      = (float4*)alloc((size_t)N * 16);
    float*  dinv   = (float*)alloc((size_t)N * 4);
    int*    rowptr = (int*)alloc((size_t)(N + 1) * 4);
    int*    cnt    = (int*)alloc((size_t)N * 4);      // histogram, then cursor
    int2*   edges  = (int2*)alloc((size_t)E * 8);
    float4* Wcp    = (float4*)alloc(HD * 16);
    float*  cbuf   = (float*)alloc(8 * 4);
    int NB = (N + 1023) / 1024;
    int*    bsums  = (int*)alloc((size_t)NB * 4);

    // CSR build
    hipMemsetAsync(cnt, 0, (size_t)N * 4, stream);
    k_hist<<<(E + 255) / 256, 256, 0, stream>>>(dst, cnt, E);
    k_scan1<<<NB, 256, 0, stream>>>(cnt, rowptr, bsums, dinv, N);
    k_scan2<<<1, 256, 0, stream>>>(bsums, NB);
    k_scan3<<<(N + 255) / 256, 256, 0, stream>>>(rowptr, cnt, bsums, N, E);
    k_scatter<<<(E + 255) / 256, 256, 0, stream>>>(src, dst, cnt, dinv, edges, E);

    // folded weights + network
    k_wc<<<1, 256, 0, stream>>>(W1, b1, W2, b2, Wout, bout, Wcp, cbuf);
    k_x0y<<<(N + 15) / 16, 256, 0, stream>>>(feat, Win, bin, Wcp, Y, N);
    k_aggA<<<(N + 255) / 256, 256, 0, stream>>>(Y, dinv, rowptr, edges, Z, N);
    k_aggB<<<(N + 255) / 256, 256, 0, stream>>>(Z, dinv, rowptr, edges, cbuf, out, N);
}